// Round 3
// baseline (317.694 us; speedup 1.0000x reference)
//
#include <hip/hip_runtime.h>
#include <hip/hip_bf16.h>

#define DEVI __device__ __forceinline__

typedef __attribute__((ext_vector_type(4))) float f32x4;
typedef __attribute__((ext_vector_type(16))) float f32x16;
typedef __attribute__((ext_vector_type(8))) short s16x8;
typedef __attribute__((ext_vector_type(4))) short s16x4;

DEVI ushort f2bf(float f) {
  union { float f; unsigned u; } v; v.f = f;
  unsigned r = v.u + 0x7FFFu + ((v.u >> 16) & 1u);
  return (ushort)(r >> 16);
}

DEVI void gload_lds16(const void* g, void* l) {
  __builtin_amdgcn_global_load_lds((const __attribute__((address_space(1))) void*)g,
                                   (__attribute__((address_space(3))) void*)l, 16, 0, 0);
}

#define MFMA16 __builtin_amdgcn_mfma_f32_16x16x32_bf16
#define SBAR() __builtin_amdgcn_s_barrier()
#define LGKM0() asm volatile("s_waitcnt lgkmcnt(0)")

// ---------------- elementwise cast ----------------
__global__ __launch_bounds__(256) void cast_bf16_k(const float* __restrict__ in,
                                                   ushort* __restrict__ out, int n) {
  int i = (blockIdx.x * 256 + threadIdx.x) * 4;
  if (i >= n) return;
  float4 v = *(const float4*)(in + i);
  ushort4 o;
  o.x = f2bf(v.x); o.y = f2bf(v.y); o.z = f2bf(v.z); o.w = f2bf(v.w);
  *(ushort4*)(out + i) = o;
}

// ---------------- transpose + cast: in (R,C) f32 -> out (C,R) bf16 ----------------
__global__ __launch_bounds__(256) void transpose_cast_k(const float* __restrict__ in,
                                                        ushort* __restrict__ out, int R, int C) {
  __shared__ ushort tile[64][66];
  const int r0 = blockIdx.y * 64, c0 = blockIdx.x * 64;
  const int tid = threadIdx.x;
  #pragma unroll
  for (int j = 0; j < 16; ++j) {
    int idx = j * 256 + tid;
    int r = idx >> 6, c = idx & 63;
    tile[c][r] = f2bf(in[(size_t)(r0 + r) * C + c0 + c]);
  }
  __syncthreads();
  #pragma unroll
  for (int j = 0; j < 16; ++j) {
    int idx = j * 256 + tid;
    int c = idx >> 6, r = idx & 63;
    out[(size_t)(c0 + c) * R + r0 + r] = tile[c][r];
  }
}

// ---------------- RoPE tables ----------------
__global__ __launch_bounds__(256) void rope_table_k(float2* __restrict__ tab) {
  int idx = blockIdx.x * 256 + threadIdx.x;   // T*32 = 65536
  int t = idx >> 5, i = idx & 31;
  float inv = expf(-(float)i * 0.28782313662425575f);  // ln(10000)/32
  float ang = (float)t * inv;
  tab[idx] = make_float2(cosf(ang), sinf(ang));
}

// =====================================================================
// 256x256 4-phase GEMM: C(M,N) = A(M,K) bf16 @ BT(N,K)^T bf16
// 8 waves (2M x 4N), wave tile 128x64, BK=64, double-buffered LDS (128 KiB).
// Phase schedule (16 MFMA each), peak 16 live fragments (64 VGPR):
//   q0: ds_read allB(8)+a0(8); stage A1(t+1); bar; lgkm0; MFMA a0*b01; bar
//   q1:                        stage B0(t+2); bar;        MFMA a0*b23; bar
//   q2: ds_read a1(8);         stage B1(t+2); bar; lgkm0; MFMA a1*b01; bar
//   q3:                        stage A0(t+2); bar;        MFMA a1*b23; vmcnt(6); bar
// Race-freedom: each staged half's last ds_read drains (lgkmcnt before MFMA)
// at a barrier preceding the stage issue.  vmcnt(6) = 3 half-tiles in flight.
// Builtin s_barrier (NOT asm+"memory": that fenced every phase, round-1/2 bug).
// EPI=0: plain f32 C store.  EPI=1: RoPE epilogue + Qp/Kp/Vp fragment pack.
// =====================================================================
template <int M, int N, int K, int EPI>
__global__ __launch_bounds__(512, 1) void gemm256(const ushort* __restrict__ A,
                                                  const ushort* __restrict__ BT,
                                                  const float2* __restrict__ tab,
                                                  float* __restrict__ C,
                                                  ushort* __restrict__ Qp,
                                                  ushort* __restrict__ Kp,
                                                  ushort* __restrict__ Vp) {
  constexpr int NKT = K / 64;
  constexpr int GX = N / 256;
  constexpr int NWG = (M / 256) * GX;
  __shared__ __attribute__((aligned(128))) ushort smem[65536];   // 128 KiB

  const int tid = threadIdx.x;
  const int ln = tid & 63, wv = tid >> 6;
  const int g = ln >> 4, l15 = ln & 15, l31 = ln & 31, hi = ln >> 5;
  const int wm = wv >> 2, wn = wv & 3;
  const int wub = tid & ~63;            // wave-uniform lane-group base

  // bijective XCD swizzle (NWG % 8 == 0 for both instantiations)
  const int orig = blockIdx.x;
  const int wg = (orig & 7) * (NWG / 8) + (orig >> 3);
  const int bx = wg % GX, by = wg / GX;
  const int m0 = by * 256, n0 = bx * 256;

  ushort* Asm = smem;                   // [buf][half][128*64]
  ushort* Bsm = smem + 32768;

  auto stageA = [&](int t, int h) {
    const ushort* gs = A + (size_t)(m0 + h * 128) * K + t * 64;
    ushort* ld = Asm + (t & 1) * 16384 + h * 8192;
    #pragma unroll
    for (int j = 0; j < 2; ++j) {
      int ci = j * 512 + tid;
      int row = ci >> 3, c = ci & 7;
      gload_lds16(gs + (size_t)row * K + ((c ^ (row & 7)) << 3),
                  ld + (size_t)(j * 512 + wub) * 8);
    }
  };
  auto stageB = [&](int t, int h) {
    const ushort* gs = BT + (size_t)(n0 + h * 128) * K + t * 64;
    ushort* ld = Bsm + (t & 1) * 16384 + h * 8192;
    #pragma unroll
    for (int j = 0; j < 2; ++j) {
      int ci = j * 512 + tid;
      int row = ci >> 3, c = ci & 7;
      gload_lds16(gs + (size_t)row * K + ((c ^ (row & 7)) << 3),
                  ld + (size_t)(j * 512 + wub) * 8);
    }
  };
  auto ldfrag = [&](const ushort* half, int row, int kc) -> s16x8 {
    return *(const s16x8*)((const char*)half + row * 128 + ((kc ^ (row & 7)) << 4));
  };

  f32x4 acc[8][4];
  #pragma unroll
  for (int i = 0; i < 8; ++i)
    #pragma unroll
    for (int j = 0; j < 4; ++j) acc[i][j] = (f32x4){0.f, 0.f, 0.f, 0.f};

  // ---- prologue: tile0 full + tile1 {B0,B1,A0} ----
  stageB(0, 0); stageB(0, 1); stageA(0, 0); stageA(0, 1);
  stageB(1, 0); stageB(1, 1); stageA(1, 0);
  asm volatile("s_waitcnt vmcnt(6)" ::: "memory");
  SBAR();

  #pragma unroll 1
  for (int t = 0; t < NKT; ++t) {
    const ushort* Ah = Asm + (t & 1) * 16384 + wm * 8192;
    const ushort* Bh = Bsm + (t & 1) * 16384 + (wn >> 1) * 8192;
    s16x8 af[4][2], bfr[4][2];

    // ---- q0: read all B + A-low; stage (t+1).A1; MFMA a0*b01 ----
    #pragma unroll
    for (int ks = 0; ks < 2; ++ks) {
      #pragma unroll
      for (int ni = 0; ni < 4; ++ni)
        bfr[ni][ks] = ldfrag(Bh, (wn & 1) * 64 + ni * 16 + l15, ks * 4 + g);
      #pragma unroll
      for (int mi = 0; mi < 4; ++mi)
        af[mi][ks] = ldfrag(Ah, mi * 16 + l15, ks * 4 + g);
    }
    if (t + 1 < NKT) stageA(t + 1, 1);
    SBAR();
    LGKM0();
    __builtin_amdgcn_s_setprio(1);
    #pragma unroll
    for (int mi = 0; mi < 4; ++mi)
      #pragma unroll
      for (int ni = 0; ni < 2; ++ni)
        #pragma unroll
        for (int ks = 0; ks < 2; ++ks)
          acc[mi][ni] = MFMA16(af[mi][ks], bfr[ni][ks], acc[mi][ni], 0, 0, 0);
    __builtin_amdgcn_s_setprio(0);
    SBAR();

    // ---- q1: stage (t+2).B0; MFMA a0*b23 ----
    if (t + 2 < NKT) stageB(t + 2, 0);
    SBAR();
    __builtin_amdgcn_s_setprio(1);
    #pragma unroll
    for (int mi = 0; mi < 4; ++mi)
      #pragma unroll
      for (int ni = 0; ni < 2; ++ni)
        #pragma unroll
        for (int ks = 0; ks < 2; ++ks)
          acc[mi][2 + ni] = MFMA16(af[mi][ks], bfr[2 + ni][ks], acc[mi][2 + ni], 0, 0, 0);
    __builtin_amdgcn_s_setprio(0);
    SBAR();

    // ---- q2: read A-high (overwrites af); stage (t+2).B1; MFMA a1*b01 ----
    #pragma unroll
    for (int ks = 0; ks < 2; ++ks)
      #pragma unroll
      for (int mi = 0; mi < 4; ++mi)
        af[mi][ks] = ldfrag(Ah, 64 + mi * 16 + l15, ks * 4 + g);
    if (t + 2 < NKT) stageB(t + 2, 1);
    SBAR();
    LGKM0();
    __builtin_amdgcn_s_setprio(1);
    #pragma unroll
    for (int mi = 0; mi < 4; ++mi)
      #pragma unroll
      for (int ni = 0; ni < 2; ++ni)
        #pragma unroll
        for (int ks = 0; ks < 2; ++ks)
          acc[4 + mi][ni] = MFMA16(af[mi][ks], bfr[ni][ks], acc[4 + mi][ni], 0, 0, 0);
    __builtin_amdgcn_s_setprio(0);
    SBAR();

    // ---- q3: stage (t+2).A0; MFMA a1*b23; counted vmcnt ----
    if (t + 2 < NKT) stageA(t + 2, 0);
    SBAR();
    __builtin_amdgcn_s_setprio(1);
    #pragma unroll
    for (int mi = 0; mi < 4; ++mi)
      #pragma unroll
      for (int ni = 0; ni < 2; ++ni)
        #pragma unroll
        for (int ks = 0; ks < 2; ++ks)
          acc[4 + mi][2 + ni] = MFMA16(af[mi][ks], bfr[2 + ni][ks], acc[4 + mi][2 + ni], 0, 0, 0);
    __builtin_amdgcn_s_setprio(0);
    if (t + 2 < NKT)      asm volatile("s_waitcnt vmcnt(6)" ::: "memory");
    else if (t + 1 < NKT) asm volatile("s_waitcnt vmcnt(0)" ::: "memory");
    SBAR();
  }

  if constexpr (EPI == 0) {
    // plain f32 store
    #pragma unroll
    for (int mi = 0; mi < 8; ++mi)
      #pragma unroll
      for (int r = 0; r < 4; ++r) {
        int row = m0 + wm * 128 + mi * 16 + g * 4 + r;
        float* crow = C + (size_t)row * N + n0 + wn * 64 + l15;
        #pragma unroll
        for (int ni = 0; ni < 4; ++ni) crow[ni * 16] = acc[mi][ni][r];
      }
  } else {
    // ---- RoPE epilogue + fragment pack (two 128-row passes through LDS) ----
    const int bq = by >> 3;              // batch
    const int tb0 = (by & 7) * 256;      // batch-local row base of this block
    const int type = (bx < 8) ? 0 : (bx < 10 ? 1 : 2);   // Q / K / V per block
    constexpr int OST = 260;             // Ot stride (elements)

    __syncthreads();                     // all waves out of the K-loop
    #pragma unroll 1
    for (int hm = 0; hm < 2; ++hm) {
      if (wm == hm) {
        #pragma unroll
        for (int mi = 0; mi < 8; ++mi)
          #pragma unroll
          for (int r = 0; r < 4; ++r) {
            const int tl = mi * 16 + g * 4 + r;
            const int t = tb0 + hm * 128 + tl;
            #pragma unroll
            for (int ni = 0; ni < 4; ++ni) {
              const int cl = wn * 64 + ni * 16 + l15;
              float val = acc[mi][ni][r], outv;
              if (type < 2) {
                float pairv = acc[mi][ni ^ 2][r];
                float2 cs = tab[t * 32 + (ni & 1) * 16 + l15];
                outv = (ni & 2) ? (val * cs.x + pairv * cs.y) : (val * cs.x - pairv * cs.y);
                if (type == 0) outv *= 0.18033688011112042f;   // 0.125 * log2(e)
              } else {
                outv = val;
              }
              smem[tl * OST + cl] = f2bf(outv);
            }
          }
      }
      __syncthreads();
      // 64 chunks for this 128-row half: id = wv*8+it
      #pragma unroll
      for (int it = 0; it < 8; ++it) {
        const int id = wv * 8 + it;
        const int hl = id >> 4, q4 = (id >> 2) & 3, fi = id & 3;
        const int tile = (by & 7) * 8 + hm * 4 + q4;
        if (type < 2) {
          const ushort* srow = smem + (q4 * 32 + l31) * OST + hl * 64 + fi * 16 + hi * 8;
          union { s16x4 h[2]; s16x8 v; } u;
          u.h[0] = *(const s16x4*)srow;
          u.h[1] = *(const s16x4*)(srow + 4);
          ushort* dst;
          if (type == 0) {
            const int h = bx * 4 + hl;
            dst = Qp + (((size_t)(bq * 32 + h) * 64 + tile) * 4 + fi) * 512 + ln * 8;
          } else {
            const int h = (bx - 8) * 4 + hl;
            dst = Kp + (((size_t)(bq * 8 + h) * 64 + tile) * 4 + fi) * 512 + ln * 8;
          }
          *(s16x8*)dst = u.v;
        } else {
          const int hk = (bx - 10) * 4 + hl;
          const int col = hl * 64 + (fi & 1) * 32 + l31;
          const int row0 = q4 * 32 + (fi >> 1) * 16 + hi * 8;
          union { ushort o[8]; s16x8 v; } u;
          #pragma unroll
          for (int j2 = 0; j2 < 8; ++j2) u.o[j2] = smem[(row0 + j2) * OST + col];
          ushort* dst = Vp + (((size_t)(bq * 8 + hk) * 64 + tile) * 4 + fi) * 512 + ln * 8;
          *(s16x8*)dst = u.v;
        }
      }
      __syncthreads();
    }
  }
}

// ---------------- causal GQA flash attention, swapped-QK^T 32x32, barrier-free ----------------
__global__ __launch_bounds__(256) void attn_k(const ushort* __restrict__ Qp,
                                              const ushort* __restrict__ Kp,
                                              const ushort* __restrict__ Vp,
                                              ushort* __restrict__ O) {
  __shared__ ushort ep[4][32 * 64];   // per-wave epilogue transpose patch
  const int tid = threadIdx.x, wv = tid >> 6, ln = tid & 63;
  const int l31 = ln & 31, hi = ln >> 5;

  const int f = blockIdx.x + gridDim.x * (blockIdx.y + 32 * blockIdx.z);  // 0..1023
  const int xcd = f & 7, j = f >> 3;         // j: 0..127
  const int pr = xcd + 8 * (j & 1);          // (b,hk) pair id, 0..15
  const int b = pr >> 3, hk = pr & 7;
  const int s = j >> 1;                      // 0..63
  const int hq = hk * 4 + (s & 3);
  const int qtile = 63 - ((s >> 2) * 4 + wv);   // LJF
  const int qw = qtile * 32;
  const int nt = qtile + 1;

  const ushort* Qh    = Qp + ((size_t)(b * 32 + hq)) * (64 * 2048);
  const ushort* Kbase = Kp + ((size_t)(b * 8 + hk)) * (64 * 2048);
  const ushort* Vbase = Vp + ((size_t)(b * 8 + hk)) * (64 * 2048);
  ushort* lds = ep[wv];

  s16x8 qf[4];
  {
    const ushort* qp_ = Qh + (size_t)qtile * 2048 + ln * 8;
    #pragma unroll
    for (int ks = 0; ks < 4; ++ks) qf[ks] = *(const s16x8*)(qp_ + ks * 512);
  }

  f32x16 oacc[2];
  #pragma unroll
  for (int dt = 0; dt < 2; ++dt)
    #pragma unroll
    for (int r = 0; r < 16; ++r) oacc[dt][r] = 0.f;
  float m = -1e30f, l = 0.f;

  const ushort* kp = Kbase + ln * 8;
  const ushort* vp = Vbase + ln * 8;

  s16x8 kf[4];
  #pragma unroll
  for (int ks = 0; ks < 4; ++ks) kf[ks] = *(const s16x8*)(kp + ks * 512);
  kp += 2048;

  s16x8 vc[4];
  union pfu { unsigned u[4]; s16x8 v; };
  pfu pf0, pf1;

  #pragma unroll 1
  for (int kt = 0; kt < nt; ++kt) {
    if (kt) {
      oacc[0] = __builtin_amdgcn_mfma_f32_32x32x16_bf16(vc[0], pf0.v, oacc[0], 0, 0, 0);
      oacc[1] = __builtin_amdgcn_mfma_f32_32x32x16_bf16(vc[1], pf0.v, oacc[1], 0, 0, 0);
      oacc[0] = __builtin_amdgcn_mfma_f32_32x32x16_bf16(vc[2], pf1.v, oacc[0], 0, 0, 0);
      oacc[1] = __builtin_amdgcn_mfma_f32_32x32x16_bf16(vc[3], pf1.v, oacc[1], 0, 0, 0);
    }
    #pragma unroll
    for (int fi2 = 0; fi2 < 4; ++fi2) vc[fi2] = *(const s16x8*)(vp + fi2 * 512);
    vp += 2048;

    f32x16 sp;
    #pragma unroll
    for (int r = 0; r < 16; ++r) sp[r] = 0.f;
    #pragma unroll
    for (int ks = 0; ks < 4; ++ks)
      sp = __builtin_amdgcn_mfma_f32_32x32x16_bf16(kf[ks], qf[ks], sp, 0, 0, 0);

    if (kt + 1 < nt) {
      #pragma unroll
      for (int ks = 0; ks < 4; ++ks) kf[ks] = *(const s16x8*)(kp + ks * 512);
      kp += 2048;
    }

    if (kt == qtile) {
      #pragma unroll
      for (int r = 0; r < 16; ++r) {
        int key = (r & 3) + 8 * (r >> 2) + 4 * hi;
        if (key > l31) sp[r] = -1e30f;
      }
    }

    float t0 = fmaxf(fmaxf(sp[0], sp[1]), sp[2]);
    float t1 = fmaxf(fmaxf(sp[3], sp[4]), sp[5]);
    float t2 = fmaxf(fmaxf(sp[6], sp[7]), sp[8]);
    float t3 = fmaxf(fmaxf(sp[9], sp[10]), sp[11]);
    float t4 = fmaxf(fmaxf(sp[12], sp[13]), sp[14]);
    float u0 = fmaxf(fmaxf(t0, t1), t2);
    float u1 = fmaxf(fmaxf(t3, t4), sp[15]);
    float pm = fmaxf(u0, u1);
    pm = fmaxf(pm, __shfl_xor(pm, 32, 64));

    if (__any(pm > m)) {
      float mn = fmaxf(m, pm);
      float alpha = __builtin_amdgcn_exp2f(m - mn);
      m = mn;
      l *= alpha;
      #pragma unroll
      for (int dt = 0; dt < 2; ++dt)
        #pragma unroll
        for (int r = 0; r < 16; ++r) oacc[dt][r] *= alpha;
    }

    #pragma unroll
    for (int r = 0; r < 16; ++r) sp[r] = __builtin_amdgcn_exp2f(sp[r] - m);
    {
      float a0 = sp[0] + sp[1], a1 = sp[2] + sp[3], a2 = sp[4] + sp[5], a3 = sp[6] + sp[7];
      float a4 = sp[8] + sp[9], a5 = sp[10] + sp[11], a6 = sp[12] + sp[13], a7 = sp[14] + sp[15];
      float b0 = a0 + a1, b1 = a2 + a3, b2 = a4 + a5, b3 = a6 + a7;
      float rs = (b0 + b1) + (b2 + b3);
      rs += __shfl_xor(rs, 32, 64);
      l += rs;
    }

    unsigned cw[8], xs[8];
    #pragma unroll
    for (int jj = 0; jj < 8; ++jj) {
      union { __hip_bfloat162 h; unsigned u; } pk;
      pk.h = __float22bfloat162_rn(make_float2(sp[2 * jj], sp[2 * jj + 1]));
      cw[jj] = pk.u;
    }
    #pragma unroll
    for (int jj = 0; jj < 8; ++jj) xs[jj] = __shfl_xor(cw[jj], 32, 64);
    pf0.u[0] = hi ? xs[2] : cw[0];
    pf0.u[1] = hi ? xs[3] : cw[1];
    pf0.u[2] = hi ? cw[2] : xs[0];
    pf0.u[3] = hi ? cw[3] : xs[1];
    pf1.u[0] = hi ? xs[6] : cw[4];
    pf1.u[1] = hi ? xs[7] : cw[5];
    pf1.u[2] = hi ? cw[6] : xs[4];
    pf1.u[3] = hi ? cw[7] : xs[5];
  }

  oacc[0] = __builtin_amdgcn_mfma_f32_32x32x16_bf16(vc[0], pf0.v, oacc[0], 0, 0, 0);
  oacc[1] = __builtin_amdgcn_mfma_f32_32x32x16_bf16(vc[1], pf0.v, oacc[1], 0, 0, 0);
  oacc[0] = __builtin_amdgcn_mfma_f32_32x32x16_bf16(vc[2], pf1.v, oacc[0], 0, 0, 0);
  oacc[1] = __builtin_amdgcn_mfma_f32_32x32x16_bf16(vc[3], pf1.v, oacc[1], 0, 0, 0);

  float invl = 1.0f / l;
  #pragma unroll
  for (int dt = 0; dt < 2; ++dt)
    #pragma unroll
    for (int r = 0; r < 16; ++r) {
      int d = dt * 32 + (r & 3) + 8 * (r >> 2) + 4 * hi;
      int byte = (l31 * 128 + d * 2) ^ ((l31 & 7) << 4);
      *(ushort*)((char*)lds + byte) = f2bf(oacc[dt][r] * invl);
    }
  const int qr = ln >> 1, half = ln & 1;
  #pragma unroll
  for (int jj = 0; jj < 4; ++jj) {
    int byte = (qr * 128 + half * 64 + jj * 16) ^ ((qr & 7) << 4);
    s16x8 vrow = *(const s16x8*)((const char*)lds + byte);
    *(s16x8*)(O + ((size_t)(b * 2048 + qw + qr)) * 2048 + hq * 64 + half * 32 + jj * 8) = vrow;
  }
}

extern "C" void kernel_launch(void* const* d_in, const int* in_sizes, int n_in,
                              void* d_out, int out_size, void* d_ws, size_t ws_size,
                              hipStream_t stream) {
  const float* x   = (const float*)d_in[0];
  const float* Wq  = (const float*)d_in[1];
  const float* Wkv = (const float*)d_in[2];
  const float* Wo  = (const float*)d_in[3];
  float* out = (float*)d_out;

  char* ws = (char*)d_ws;
  ushort* xb     = (ushort*)(ws);                 // 16 MiB  x bf16 (4096x2048)
  ushort* WqkvT  = (ushort*)(ws + 16777216);      // 12 MiB  [Wq|Wkv]^T bf16 (3072x2048)
  ushort* WoT    = (ushort*)(ws + 29360128);      //  8 MiB  Wo^T bf16 (2048x2048)
  float2* tab    = (float2*)(ws + 37748736);      // 512 KiB rope tables
  ushort* Qp     = (ushort*)(ws + 38273024);      // 16 MiB  Q packed
  ushort* Kp     = (ushort*)(ws + 55050240);      //  4 MiB  K packed
  ushort* Vp     = (ushort*)(ws + 59244544);      //  4 MiB  V packed
  ushort* Ob     = (ushort*)(ws + 63438848);      // 16 MiB  attn out bf16 (4096x2048)

  cast_bf16_k<<<8192, 256, 0, stream>>>(x, xb, 2 * 2048 * 2048);
  transpose_cast_k<<<dim3(32, 32), 256, 0, stream>>>(Wq, WqkvT, 2048, 2048);
  transpose_cast_k<<<dim3(16, 32), 256, 0, stream>>>(Wkv, WqkvT + 2048 * 2048, 2048, 1024);
  transpose_cast_k<<<dim3(32, 32), 256, 0, stream>>>(Wo, WoT, 2048, 2048);
  rope_table_k<<<256, 256, 0, stream>>>(tab);
  gemm256<4096, 3072, 2048, 1><<<192, 512, 0, stream>>>(xb, WqkvT, tab, (float*)nullptr, Qp, Kp, Vp);
  attn_k<<<dim3(16, 32, 2), 256, 0, stream>>>(Qp, Kp, Vp, Ob);
  gemm256<4096, 2048, 2048, 0><<<128, 512, 0, stream>>>(Ob, WoT, (const float2*)nullptr, out,
                                                        (ushort*)nullptr, (ushort*)nullptr, (ushort*)nullptr);
}

// Round 4
// 261.376 us; speedup vs baseline: 1.2155x; 1.2155x over previous
//
#include <hip/hip_runtime.h>
#include <hip/hip_bf16.h>

#define DEVI __device__ __forceinline__

typedef __attribute__((ext_vector_type(4))) float f32x4;
typedef __attribute__((ext_vector_type(16))) float f32x16;
typedef __attribute__((ext_vector_type(8))) short s16x8;
typedef __attribute__((ext_vector_type(4))) short s16x4;

DEVI ushort f2bf(float f) {
  union { float f; unsigned u; } v; v.f = f;
  unsigned r = v.u + 0x7FFFu + ((v.u >> 16) & 1u);
  return (ushort)(r >> 16);
}

DEVI void gload_lds16(const void* g, void* l) {
  __builtin_amdgcn_global_load_lds((const __attribute__((address_space(1))) void*)g,
                                   (__attribute__((address_space(3))) void*)l, 16, 0, 0);
}

#define MFMA16 __builtin_amdgcn_mfma_f32_16x16x32_bf16
#define SBAR() __builtin_amdgcn_s_barrier()
#define LGKM0() asm volatile("s_waitcnt lgkmcnt(0)")

// Stage NITER*256 16B chunks into LDS. Tile rows are 64 bf16 = 128B (8 chunks).
template <int NITER>
DEVI void stage_swz(const ushort* __restrict__ gsrc, int stride_elems, ushort* lds, int tid) {
  const int wv = tid >> 6, ln = tid & 63;
  #pragma unroll
  for (int j = 0; j < NITER; ++j) {
    const int ci = j * 256 + wv * 64 + ln;
    const int row = ci >> 3, c = ci & 7;
    const ushort* src = gsrc + (size_t)row * stride_elems + ((c ^ (row & 7)) << 3);
    gload_lds16(src, lds + (size_t)(j * 256 + wv * 64) * 8);
  }
}

DEVI s16x8 frag_swz(const ushort* lds_tile, int row, int chunk) {
  const int off = row * 128 + ((chunk ^ (row & 7)) << 4);
  return *(const s16x8*)((const char*)lds_tile + off);
}

// ---------------- elementwise cast ----------------
__global__ __launch_bounds__(256) void cast_bf16_k(const float* __restrict__ in,
                                                   ushort* __restrict__ out, int n) {
  int i = (blockIdx.x * 256 + threadIdx.x) * 4;
  if (i >= n) return;
  float4 v = *(const float4*)(in + i);
  ushort4 o;
  o.x = f2bf(v.x); o.y = f2bf(v.y); o.z = f2bf(v.z); o.w = f2bf(v.w);
  *(ushort4*)(out + i) = o;
}

// ---------------- transpose + cast: in (R,C) f32 -> out (C,R) bf16 ----------------
__global__ __launch_bounds__(256) void transpose_cast_k(const float* __restrict__ in,
                                                        ushort* __restrict__ out, int R, int C) {
  __shared__ ushort tile[64][66];
  const int r0 = blockIdx.y * 64, c0 = blockIdx.x * 64;
  const int tid = threadIdx.x;
  #pragma unroll
  for (int j = 0; j < 16; ++j) {
    int idx = j * 256 + tid;
    int r = idx >> 6, c = idx & 63;
    tile[c][r] = f2bf(in[(size_t)(r0 + r) * C + c0 + c]);
  }
  __syncthreads();
  #pragma unroll
  for (int j = 0; j < 16; ++j) {
    int idx = j * 256 + tid;
    int c = idx >> 6, r = idx & 63;
    out[(size_t)(c0 + c) * R + r0 + r] = tile[c][r];
  }
}

// ---------------- RoPE tables ----------------
__global__ __launch_bounds__(256) void rope_table_k(float2* __restrict__ tab) {
  int idx = blockIdx.x * 256 + threadIdx.x;   // T*32 = 65536
  int t = idx >> 5, i = idx & 31;
  float inv = expf(-(float)i * 0.28782313662425575f);  // ln(10000)/32
  float ang = (float)t * inv;
  tab[idx] = make_float2(cosf(ang), sinf(ang));
}

// ---------------- fused QKV GEMM (round-0 proven 128x128 m97-structure) ----------------
__global__ __launch_bounds__(256) void gemm_qkv_fused(const ushort* __restrict__ A,
                                                      const ushort* __restrict__ BT,
                                                      const float2* __restrict__ tab,
                                                      ushort* __restrict__ Qp,
                                                      ushort* __restrict__ Kp,
                                                      ushort* __restrict__ Vp) {
  const int K = 2048;
  __shared__ __align__(128) ushort smem[128 * 132];   // 33 KB: staging / out-tile union
  ushort* As = smem;
  ushort* Bs = smem + 8192;
  ushort* Ot = smem;                                   // [128][132] bf16 out tile
  const int tid = threadIdx.x;
  const int ln = tid & 63, wv = tid >> 6;
  const int g = ln >> 4, l15 = ln & 15;
  const int l31 = ln & 31, hi = ln >> 5;
  const int wm = wv >> 1, wn = wv & 1;
  const int m0 = blockIdx.y * 128, n0 = blockIdx.x * 128;

  f32x4 zero = {0.f, 0.f, 0.f, 0.f};
  f32x4 acc[4][4];
  #pragma unroll
  for (int i = 0; i < 4; ++i)
    #pragma unroll
    for (int j = 0; j < 4; ++j) acc[i][j] = zero;

  for (int kt = 0; kt < K; kt += 64) {
    __syncthreads();
    stage_swz<4>(A + (size_t)m0 * K + kt, K, As, tid);
    stage_swz<4>(BT + (size_t)n0 * K + kt, K, Bs, tid);
    __syncthreads();
    #pragma unroll
    for (int ks = 0; ks < 2; ++ks) {
      s16x8 af[4], bfr[4];
      #pragma unroll
      for (int mi = 0; mi < 4; ++mi) af[mi] = frag_swz(As, wm * 64 + mi * 16 + l15, ks * 4 + g);
      #pragma unroll
      for (int ni = 0; ni < 4; ++ni) bfr[ni] = frag_swz(Bs, wn * 64 + ni * 16 + l15, ks * 4 + g);
      #pragma unroll
      for (int mi = 0; mi < 4; ++mi)
        #pragma unroll
        for (int ni = 0; ni < 4; ++ni)
          acc[mi][ni] = __builtin_amdgcn_mfma_f32_16x16x32_bf16(af[mi], bfr[ni], acc[mi][ni], 0, 0, 0);
    }
  }

  // ---- epilogue: RoPE in-register, bf16 tile to LDS, packed chunk stores ----
  __syncthreads();                 // all waves done reading As/Bs
  const int bq = m0 >> 11;         // batch (block-uniform)
  const int tg0 = m0 & 2047;       // first global t of this block
  const int type = (n0 < 2048) ? 0 : (n0 < 2560 ? 1 : 2);   // Q / K / V (block-uniform)

  #pragma unroll
  for (int mi = 0; mi < 4; ++mi)
    #pragma unroll
    for (int r = 0; r < 4; ++r) {
      const int tl = wm * 64 + mi * 16 + g * 4 + r;       // local t row
      const int t = tg0 + tl;
      #pragma unroll
      for (int ni = 0; ni < 4; ++ni) {
        const int cl = wn * 64 + ni * 16 + l15;           // local col
        float val = acc[mi][ni][r];
        float outv;
        if (type < 2) {                                    // RoPE (Q and K)
          float pairv = acc[mi][ni ^ 2][r];
          float2 cs = tab[t * 32 + (ni & 1) * 16 + l15];
          outv = (ni & 2) ? (val * cs.x + pairv * cs.y) : (val * cs.x - pairv * cs.y);
          if (type == 0) outv *= 0.18033688011112042f;     // 0.125 * log2(e)
        } else {
          outv = val;
        }
        Ot[tl * 132 + cl] = f2bf(outv);
      }
    }
  __syncthreads();

  // 32 chunks: id = wv*8+it -> hl = id>>4 (head-local), q4 = (id>>2)&3 (tile), fi = id&3
  #pragma unroll
  for (int it = 0; it < 8; ++it) {
    const int id = wv * 8 + it;
    const int hl = id >> 4, q4 = (id >> 2) & 3, fi = id & 3;
    const int tile = (tg0 >> 5) + q4;
    if (type < 2) {
      // Q/K frag: t = tile*32 + (ln&31), dh = fi*16 + (ln>>5)*8 + j
      const ushort* srow = Ot + (q4 * 32 + l31) * 132 + hl * 64 + fi * 16 + hi * 8;
      union { s16x4 h[2]; s16x8 v; } u;
      u.h[0] = *(const s16x4*)srow;
      u.h[1] = *(const s16x4*)(srow + 4);
      ushort* dst;
      if (type == 0) {
        const int h = (n0 >> 6) + hl;
        dst = Qp + (((size_t)(bq * 32 + h) * 64 + tile) * 4 + fi) * 512 + ln * 8;
      } else {
        const int h = ((n0 - 2048) >> 6) + hl;
        dst = Kp + (((size_t)(bq * 8 + h) * 64 + tile) * 4 + fi) * 512 + ln * 8;
      }
      *(s16x8*)dst = u.v;
    } else {
      // V frag: t = tile*32 + (fi>>1)*16 + (ln>>5)*8 + j, d = (fi&1)*32 + (ln&31)
      const int hk = ((n0 - 2560) >> 6) + hl;
      const int col = hl * 64 + (fi & 1) * 32 + l31;
      const int row0 = q4 * 32 + (fi >> 1) * 16 + hi * 8;
      ushort o[8];
      #pragma unroll
      for (int j = 0; j < 8; ++j) o[j] = Ot[(row0 + j) * 132 + col];
      ushort* dst = Vp + (((size_t)(bq * 8 + hk) * 64 + tile) * 4 + fi) * 512 + ln * 8;
      *(s16x8*)dst = *(const s16x8*)o;
    }
  }
}

// =====================================================================
// Wo GEMM, 256x256 8-phase experiment: C(4096,2048) = A@(2048,2048)^T.
// Identical schedule to round-3 (functionally verified there; absmax matched).
// ONE change: amdgpu_waves_per_eu(2,2) instead of __launch_bounds__ — pins the
// register allocator's occupancy target to 2 waves/EU (256-VGPR budget).
// Rounds 1-3 showed the allocator targeting 4 waves/EU (128-reg cap) and
// spilling ~80 regs/thread (~115 MB anomalous HBM writes, MfmaUtil 13%).
// =====================================================================
__global__ __attribute__((amdgpu_flat_work_group_size(512, 512)))
__attribute__((amdgpu_waves_per_eu(2, 2)))
void gemm_bt_8ph(const ushort* __restrict__ A,
                 const ushort* __restrict__ BT,
                 float* __restrict__ C) {
  constexpr int M = 4096, N = 2048, K = 2048;
  constexpr int NKT = K / 64;           // 32
  constexpr int GX = N / 256;           // 8
  constexpr int NWG = (M / 256) * GX;   // 128
  __shared__ __attribute__((aligned(128))) ushort smem[65536];   // 128 KiB

  const int tid = threadIdx.x;
  const int ln = tid & 63, wv = tid >> 6;
  const int g = ln >> 4, l15 = ln & 15;
  const int wm = wv >> 2, wn = wv & 3;
  const int wub = tid & ~63;

  const int orig = blockIdx.x;
  const int wg = (orig & 7) * (NWG / 8) + (orig >> 3);   // bijective XCD swizzle
  const int bx = wg % GX, by = wg / GX;
  const int m0 = by * 256, n0 = bx * 256;

  ushort* Asm = smem;                   // [buf][half][128*64]
  ushort* Bsm = smem + 32768;

  auto stageA = [&](int t, int h) {
    const ushort* gs = A + (size_t)(m0 + h * 128) * K + t * 64;
    ushort* ld = Asm + (t & 1) * 16384 + h * 8192;
    #pragma unroll
    for (int j = 0; j < 2; ++j) {
      int ci = j * 512 + tid;
      int row = ci >> 3, c = ci & 7;
      gload_lds16(gs + (size_t)row * K + ((c ^ (row & 7)) << 3),
                  ld + (size_t)(j * 512 + wub) * 8);
    }
  };
  auto stageB = [&](int t, int h) {
    const ushort* gs = BT + (size_t)(n0 + h * 128) * K + t * 64;
    ushort* ld = Bsm + (t & 1) * 16384 + h * 8192;
    #pragma unroll
    for (int j = 0; j < 2; ++j) {
      int ci = j * 512 + tid;
      int row = ci >> 3, c = ci & 7;
      gload_lds16(gs + (size_t)row * K + ((c ^ (row & 7)) << 3),
                  ld + (size_t)(j * 512 + wub) * 8);
    }
  };
  auto ldfrag = [&](const ushort* half, int row, int kc) -> s16x8 {
    return *(const s16x8*)((const char*)half + row * 128 + ((kc ^ (row & 7)) << 4));
  };

  f32x4 acc[8][4];
  #pragma unroll
  for (int i = 0; i < 8; ++i)
    #pragma unroll
    for (int j = 0; j < 4; ++j) acc[i][j] = (f32x4){0.f, 0.f, 0.f, 0.f};

  // ---- prologue: tile0 full + tile1 {B0,B1,A0} ----
  stageB(0, 0); stageB(0, 1); stageA(0, 0); stageA(0, 1);
  stageB(1, 0); stageB(1, 1); stageA(1, 0);
  asm volatile("s_waitcnt vmcnt(6)" ::: "memory");
  SBAR();

  #pragma unroll 1
  for (int t = 0; t < NKT; ++t) {
    const ushort* Ah = Asm + (t & 1) * 16384 + wm * 8192;
    const ushort* Bh = Bsm + (t & 1) * 16384 + (wn >> 1) * 8192;
    s16x8 af[4][2], bfr[4][2];

    // ---- q0: read all B + A-low; stage (t+1).A1; MFMA a0*b01 ----
    #pragma unroll
    for (int ks = 0; ks < 2; ++ks) {
      #pragma unroll
      for (int ni = 0; ni < 4; ++ni)
        bfr[ni][ks] = ldfrag(Bh, (wn & 1) * 64 + ni * 16 + l15, ks * 4 + g);
      #pragma unroll
      for (int mi = 0; mi < 4; ++mi)
        af[mi][ks] = ldfrag(Ah, mi * 16 + l15, ks * 4 + g);
    }
    if (t + 1 < NKT) stageA(t + 1, 1);
    SBAR();
    LGKM0();
    __builtin_amdgcn_s_setprio(1);
    #pragma unroll
    for (int mi = 0; mi < 4; ++mi)
      #pragma unroll
      for (int ni = 0; ni < 2; ++ni)
        #pragma unroll
        for (int ks = 0; ks < 2; ++ks)
          acc[mi][ni] = MFMA16(af[mi][ks], bfr[ni][ks], acc[mi][ni], 0, 0, 0);
    __builtin_amdgcn_s_setprio(0);
    SBAR();

    // ---- q1: stage (t+2).B0; MFMA a0*b23 ----
    if (t + 2 < NKT) stageB(t + 2, 0);
    SBAR();
    __builtin_amdgcn_s_setprio(1);
    #pragma unroll
    for (int mi = 0; mi < 4; ++mi)
      #pragma unroll
      for (int ni = 0; ni < 2; ++ni)
        #pragma unroll
        for (int ks = 0; ks < 2; ++ks)
          acc[mi][2 + ni] = MFMA16(af[mi][ks], bfr[2 + ni][ks], acc[mi][2 + ni], 0, 0, 0);
    __builtin_amdgcn_s_setprio(0);
    SBAR();

    // ---- q2: read A-high (reuse af); stage (t+2).B1; MFMA a1*b01 ----
    #pragma unroll
    for (int ks = 0; ks < 2; ++ks)
      #pragma unroll
      for (int mi = 0; mi < 4; ++mi)
        af[mi][ks] = ldfrag(Ah, 64 + mi * 16 + l15, ks * 4 + g);
    if (t + 2 < NKT) stageB(t + 2, 1);
    SBAR();
    LGKM0();
    __builtin_amdgcn_s_setprio(1);
    #pragma unroll
    for (int mi = 0; mi < 4; ++mi)
      #pragma unroll
      for (int ni = 0; ni < 2; ++ni)
        #pragma unroll
        for (int ks = 0; ks < 2; ++ks)
          acc[4 + mi][ni] = MFMA16(af[mi][ks], bfr[ni][ks], acc[4 + mi][ni], 0, 0, 0);
    __builtin_amdgcn_s_setprio(0);
    SBAR();

    // ---- q3: stage (t+2).A0; MFMA a1*b23; counted vmcnt ----
    if (t + 2 < NKT) stageA(t + 2, 0);
    SBAR();
    __builtin_amdgcn_s_setprio(1);
    #pragma unroll
    for (int mi = 0; mi < 4; ++mi)
      #pragma unroll
      for (int ni = 0; ni < 2; ++ni)
        #pragma unroll
        for (int ks = 0; ks < 2; ++ks)
          acc[4 + mi][2 + ni] = MFMA16(af[mi][ks], bfr[2 + ni][ks], acc[4 + mi][2 + ni], 0, 0, 0);
    __builtin_amdgcn_s_setprio(0);
    if (t + 2 < NKT)      asm volatile("s_waitcnt vmcnt(6)" ::: "memory");
    else if (t + 1 < NKT) asm volatile("s_waitcnt vmcnt(0)" ::: "memory");
    SBAR();
  }

  // plain f32 store
  #pragma unroll
  for (int mi = 0; mi < 8; ++mi)
    #pragma unroll
    for (int r = 0; r < 4; ++r) {
      int row = m0 + wm * 128 + mi * 16 + g * 4 + r;
      float* crow = C + (size_t)row * N + n0 + wn * 64 + l15;
      #pragma unroll
      for (int ni = 0; ni < 4; ++ni) crow[ni * 16] = acc[mi][ni][r];
    }
}

// ---------------- causal GQA flash attention, swapped-QK^T 32x32, barrier-free ----------------
__global__ __launch_bounds__(256) void attn_k(const ushort* __restrict__ Qp,
                                              const ushort* __restrict__ Kp,
                                              const ushort* __restrict__ Vp,
                                              ushort* __restrict__ O) {
  __shared__ ushort ep[4][32 * 64];   // per-wave epilogue transpose patch
  const int tid = threadIdx.x, wv = tid >> 6, ln = tid & 63;
  const int l31 = ln & 31, hi = ln >> 5;

  const int f = blockIdx.x + gridDim.x * (blockIdx.y + 32 * blockIdx.z);  // 0..1023
  const int xcd = f & 7, j = f >> 3;         // j: 0..127
  const int pr = xcd + 8 * (j & 1);          // (b,hk) pair id, 0..15
  const int b = pr >> 3, hk = pr & 7;
  const int s = j >> 1;                      // 0..63
  const int hq = hk * 4 + (s & 3);
  const int qtile = 63 - ((s >> 2) * 4 + wv);   // LJF
  const int qw = qtile * 32;
  const int nt = qtile + 1;

  const ushort* Qh    = Qp + ((size_t)(b * 32 + hq)) * (64 * 2048);
  const ushort* Kbase = Kp + ((size_t)(b * 8 + hk)) * (64 * 2048);
  const ushort* Vbase = Vp + ((size_t)(b * 8 + hk)) * (64 * 2048);
  ushort* lds = ep[wv];

  s16x8 qf[4];
  {
    const ushort* qp_ = Qh + (size_t)qtile * 2048 + ln * 8;
    #pragma unroll
    for (int ks = 0; ks < 4; ++ks) qf[ks] = *(const s16x8*)(qp_ + ks * 512);
  }

  f32x16 oacc[2];
  #pragma unroll
  for (int dt = 0; dt < 2; ++dt)
    #pragma unroll
    for (int r = 0; r < 16; ++r) oacc[dt][r] = 0.f;
  float m = -1e30f, l = 0.f;

  const ushort* kp = Kbase + ln * 8;
  const ushort* vp = Vbase + ln * 8;

  s16x8 kf[4];
  #pragma unroll
  for (int ks = 0; ks < 4; ++ks) kf[ks] = *(const s16x8*)(kp + ks * 512);
  kp += 2048;

  s16x8 vc[4];
  union pfu { unsigned u[4]; s16x8 v; };
  pfu pf0, pf1;

  #pragma unroll 1
  for (int kt = 0; kt < nt; ++kt) {
    if (kt) {
      __builtin_amdgcn_s_setprio(1);
      oacc[0] = __builtin_amdgcn_mfma_f32_32x32x16_bf16(vc[0], pf0.v, oacc[0], 0, 0, 0);
      oacc[1] = __builtin_amdgcn_mfma_f32_32x32x16_bf16(vc[1], pf0.v, oacc[1], 0, 0, 0);
      oacc[0] = __builtin_amdgcn_mfma_f32_32x32x16_bf16(vc[2], pf1.v, oacc[0], 0, 0, 0);
      oacc[1] = __builtin_amdgcn_mfma_f32_32x32x16_bf16(vc[3], pf1.v, oacc[1], 0, 0, 0);
      __builtin_amdgcn_s_setprio(0);
    }
    #pragma unroll
    for (int fi2 = 0; fi2 < 4; ++fi2) vc[fi2] = *(const s16x8*)(vp + fi2 * 512);
    vp += 2048;

    f32x16 sp;
    #pragma unroll
    for (int r = 0; r < 16; ++r) sp[r] = 0.f;
    __builtin_amdgcn_s_setprio(1);
    #pragma unroll
    for (int ks = 0; ks < 4; ++ks)
      sp = __builtin_amdgcn_mfma_f32_32x32x16_bf16(kf[ks], qf[ks], sp, 0, 0, 0);
    __builtin_amdgcn_s_setprio(0);

    if (kt + 1 < nt) {
      #pragma unroll
      for (int ks = 0; ks < 4; ++ks) kf[ks] = *(const s16x8*)(kp + ks * 512);
      kp += 2048;
    }

    if (kt == qtile) {
      #pragma unroll
      for (int r = 0; r < 16; ++r) {
        int key = (r & 3) + 8 * (r >> 2) + 4 * hi;
        if (key > l31) sp[r] = -1e30f;
      }
    }

    float t0 = fmaxf(fmaxf(sp[0], sp[1]), sp[2]);
    float t1 = fmaxf(fmaxf(sp[3], sp[4]), sp[5]);
    float t2 = fmaxf(fmaxf(sp[6], sp[7]), sp[8]);
    float t3 = fmaxf(fmaxf(sp[9], sp[10]), sp[11]);
    float t4 = fmaxf(fmaxf(sp[12], sp[13]), sp[14]);
    float u0 = fmaxf(fmaxf(t0, t1), t2);
    float u1 = fmaxf(fmaxf(t3, t4), sp[15]);
    float pm = fmaxf(u0, u1);
    pm = fmaxf(pm, __shfl_xor(pm, 32, 64));

    if (__any(pm > m)) {
      float mn = fmaxf(m, pm);
      float alpha = __builtin_amdgcn_exp2f(m - mn);
      m = mn;
      l *= alpha;
      #pragma unroll
      for (int dt = 0; dt < 2; ++dt)
        #pragma unroll
        for (int r = 0; r < 16; ++r) oacc[dt][r] *= alpha;
    }

    #pragma unroll
    for (int r = 0; r < 16; ++r) sp[r] = __builtin_amdgcn_exp2f(sp[r] - m);
    {
      float a0 = sp[0] + sp[1], a1 = sp[2] + sp[3], a2 = sp[4] + sp[5], a3 = sp[6] + sp[7];
      float a4 = sp[8] + sp[9], a5 = sp[10] + sp[11], a6 = sp[12] + sp[13], a7 = sp[14] + sp[15];
      float b0 = a0 + a1, b1 = a2 + a3, b2 = a4 + a5, b3 = a6 + a7;
      float rs = (b0 + b1) + (b2 + b3);
      rs += __shfl_xor(rs, 32, 64);
      l += rs;
    }

    unsigned cw[8], xs[8];
    #pragma unroll
    for (int jj = 0; jj < 8; ++jj) {
      union { __hip_bfloat162 h; unsigned u; } pk;
      pk.h = __float22bfloat162_rn(make_float2(sp[2 * jj], sp[2 * jj + 1]));
      cw[jj] = pk.u;
    }
    #pragma unroll
    for (int jj = 0; jj < 8; ++jj) xs[jj] = __shfl_xor(cw[jj], 32, 64);
    pf0.u[0] = hi ? xs[2] : cw[0];
    pf0.u[1] = hi ? xs[3] : cw[1];
    pf0.u[2] = hi ? cw[2] : xs[0];
    pf0.u[3] = hi ? cw[3] : xs[1];
    pf1.u[0] = hi ? xs[6] : cw[4];
    pf1.u[1] = hi ? xs[7] : cw[5];
    pf1.u[2] = hi ? cw[6] : xs[4];
    pf1.u[3] = hi ? cw[7] : xs[5];
  }

  __builtin_amdgcn_s_setprio(1);
  oacc[0] = __builtin_amdgcn_mfma_f32_32x32x16_bf16(vc[0], pf0.v, oacc[0], 0, 0, 0);
  oacc[1] = __builtin_amdgcn_mfma_f32_32x32x16_bf16(vc[1], pf0.v, oacc[1], 0, 0, 0);
  oacc[0] = __builtin_amdgcn_mfma_f32_32x32x16_bf16(vc[2], pf1.v, oacc[0], 0, 0, 0);
  oacc[1] = __builtin_amdgcn_mfma_f32_32x32x16_bf16(vc[3], pf1.v, oacc[1], 0, 0, 0);
  __builtin_amdgcn_s_setprio(0);

  float invl = 1.0f / l;
  #pragma unroll
  for (int dt = 0; dt < 2; ++dt)
    #pragma unroll
    for (int r = 0; r < 16; ++r) {
      int d = dt * 32 + (r & 3) + 8 * (r >> 2) + 4 * hi;
      int byte = (l31 * 128 + d * 2) ^ ((l31 & 7) << 4);
      *(ushort*)((char*)lds + byte) = f2bf(oacc[dt][r] * invl);
    }
  const int qr = ln >> 1, half = ln & 1;
  #pragma unroll
  for (int jj = 0; jj < 4; ++jj) {
    int byte = (qr * 128 + half * 64 + jj * 16) ^ ((qr & 7) << 4);
    s16x8 vrow = *(const s16x8*)((const char*)lds + byte);
    *(s16x8*)(O + ((size_t)(b * 2048 + qw + qr)) * 2048 + hq * 64 + half * 32 + jj * 8) = vrow;
  }
}

extern "C" void kernel_launch(void* const* d_in, const int* in_sizes, int n_in,
                              void* d_out, int out_size, void* d_ws, size_t ws_size,
                              hipStream_t stream) {
  const float* x   = (const float*)d_in[0];
  const float* Wq  = (const float*)d_in[1];
  const float* Wkv = (const float*)d_in[2];
  const float* Wo  = (const float*)d_in[3];
  float* out = (float*)d_out;

  char* ws = (char*)d_ws;
  ushort* xb     = (ushort*)(ws);                 // 16 MiB  x bf16 (4096x2048)
  ushort* WqkvT  = (ushort*)(ws + 16777216);      // 12 MiB  [Wq|Wkv]^T bf16 (3072x2048)
  ushort* WoT    = (ushort*)(ws + 29360128);      //  8 MiB  Wo^T bf16 (2048x2048)
  float2* tab    = (float2*)(ws + 37748736);      // 512 KiB rope tables
  ushort* Qp     = (ushort*)(ws + 38273024);      // 16 MiB  Q packed
  ushort* Kp     = (ushort*)(ws + 55050240);      //  4 MiB  K packed
  ushort* Vp     = (ushort*)(ws + 59244544);      //  4 MiB  V packed
  ushort* Ob     = (ushort*)(ws + 63438848);      // 16 MiB  attn out bf16 (4096x2048)

  cast_bf16_k<<<8192, 256, 0, stream>>>(x, xb, 2 * 2048 * 2048);
  transpose_cast_k<<<dim3(32, 32), 256, 0, stream>>>(Wq, WqkvT, 2048, 2048);
  transpose_cast_k<<<dim3(16, 32), 256, 0, stream>>>(Wkv, WqkvT + 2048 * 2048, 2048, 1024);
  transpose_cast_k<<<dim3(32, 32), 256, 0, stream>>>(Wo, WoT, 2048, 2048);
  rope_table_k<<<256, 256, 0, stream>>>(tab);
  gemm_qkv_fused<<<dim3(24, 32), 256, 0, stream>>>(xb, WqkvT, tab, Qp, Kp, Vp);
  attn_k<<<dim3(16, 32, 2), 256, 0, stream>>>(Qp, Kp, Vp, Ob);
  gemm_bt_8ph<<<128, 512, 0, stream>>>(Ob, WoT, out);
}